// Round 16
// baseline (337.351 us; speedup 1.0000x reference)
//
#include <hip/hip_runtime.h>
#include <hip/hip_bf16.h>
#include <math.h>

// ---------------------------------------------------------------------------
// R16 = R15 + W-fragment prefetch across the barrier:
//   conv12g's 8 L2 loads were issued after the barrier, gating the first MFMA
//   (~200-300cy exposed, 2x/sample). Now issued into wfp[8] registers BEFORE
//   mix_epi (overlapping the LN shuffle chain + barrier drain).
//   Reg check: ~116 unified + 32 = ~148 < 170 budget at (256,3) -> no spill.
// If neutral: kernel is at its structural plateau (VALU-issue bound at 49%
//   with barrier-serialized phases; next step would be a ground-up 2-sample
//   wave-specialized pipeline).
// ---------------------------------------------------------------------------

typedef __bf16 bf16x8 __attribute__((ext_vector_type(8)));
typedef float  f32x4  __attribute__((ext_vector_type(4)));
typedef unsigned int u32x4 __attribute__((ext_vector_type(4)));
typedef unsigned int u32x2 __attribute__((ext_vector_type(2)));

#define DEVINL __device__ __forceinline__
#define HROW 400   // hws row stride (floats); cols 392..399 zero-padded

DEVINL unsigned bfr(float x) {             // float -> bf16 bits (RNE) — cold paths
    unsigned u = __float_as_uint(x);
    return (u + 0x7fffu + ((u >> 16) & 1u)) >> 16;
}
DEVINL unsigned pk2(float a, float b) {    // v_cvt_pk_bf16_f32
    float2 f; f.x = a; f.y = b;
    __hip_bfloat162 h = __float22bfloat162_rn(f);
    unsigned u;
    __builtin_memcpy(&u, &h, sizeof(u));
    return u;
}
DEVINL unsigned short bf1(float x) {       // single f32 -> bf16: 1 cvt_pk inst
    return (unsigned short)pk2(x, x);
}

DEVINL f32x4 MFMA(u32x4 a, u32x4 b, f32x4 c) {
    return __builtin_amdgcn_mfma_f32_16x16x32_bf16(
        __builtin_bit_cast(bf16x8, a), __builtin_bit_cast(bf16x8, b), c, 0, 0, 0);
}

#define TS 36   // Tlds / Amlds row stride in u32 (pairs of bf16)
#define HS 68   // Hlds row stride in u32
// staggered Tlds row base (dwords)
DEVINL int TROW(int r) { return r * TS + ((r >> 3) & 1) * 4; }

// prefetch the 8 W-fragments for the NEXT conv phase into registers
DEVINL void prefW(u32x4 (&wfp)[8], const u32x4* __restrict__ Wp, int w, int l)
{
    #pragma unroll
    for (int ks = 0; ks < 4; ++ks) {
        wfp[2 * ks]     = Wp[((2 * w + 0) * 4 + ks) * 64 + l];
        wfp[2 * ks + 1] = Wp[((2 * w + 1) * 4 + ks) * 64 + l];
    }
}

// conv layers 1,2 with prefetched W-frags: rg[m2*4+ut] = (W^T)_tile x H-as-B
DEVINL void conv12p(f32x4 (&rg)[8], const unsigned* Hlds,
                    const u32x4 (&wfp)[8], int g, int c15)
{
    #pragma unroll
    for (int i = 0; i < 8; ++i) rg[i] = (f32x4){0.f, 0.f, 0.f, 0.f};
    #pragma unroll
    for (int ks = 0; ks < 4; ++ks) {
        u32x4 hb[4];
        #pragma unroll
        for (int ut = 0; ut < 4; ++ut)
            hb[ut] = *(const u32x4*)&Hlds[(ut * 16 + c15) * HS + ks * 16 + g * 4];
        #pragma unroll
        for (int ut = 0; ut < 4; ++ut) {
            rg[ut]     = MFMA(wfp[2 * ks],     hb[ut], rg[ut]);
            rg[4 + ut] = MFMA(wfp[2 * ks + 1], hb[ut], rg[4 + ut]);
        }
    }
}

// conv0: X (global) -> bf16 A-frags -> rg (K=16 zero-padded to 32)
DEVINL void conv0g(f32x4 (&rg)[8], const float* __restrict__ X, int n,
                   const u32x4 (&W0f)[2], int g, int c15)
{
    #pragma unroll
    for (int i = 0; i < 8; ++i) rg[i] = (f32x4){0.f, 0.f, 0.f, 0.f};
    #pragma unroll
    for (int ut = 0; ut < 4; ++ut) {
        const int u = ut * 16 + c15;
        u32x4 xb = (u32x4){0u, 0u, 0u, 0u};
        if (g < 2 && u < 54) {
            const f32x4* xp = (const f32x4*)(X + (size_t)n * 864 + u * 16 + g * 8);
            f32x4 f0 = xp[0], f1 = xp[1];
            xb = (u32x4){pk2(f0[0], f0[1]), pk2(f0[2], f0[3]),
                         pk2(f1[0], f1[1]), pk2(f1[2], f1[3])};
        }
        rg[ut]     = MFMA(W0f[0], xb, rg[ut]);
        rg[4 + ut] = MFMA(W0f[1], xb, rg[4 + ut]);
    }
}

// conv epilogue: rg + bias -> Tlds (staggered rows), direct b16 scatter
DEVINL void conv_epi(const f32x4 (&rg)[8], unsigned short* TldsH, const float* bias,
                     int w, int g, int c15)
{
    #pragma unroll
    for (int m2 = 0; m2 < 2; ++m2) {
        const int chb = (2 * w + m2) * 16;
        f32x4 bb = *(const f32x4*)&bias[chb + g * 4];
        #pragma unroll
        for (int ut = 0; ut < 4; ++ut) {
            const int u = ut * 16 + c15;
            #pragma unroll
            for (int r = 0; r < 4; ++r)
                TldsH[TROW(chb + g * 4 + r) * 2 + u] = bf1(rg[m2 * 4 + ut][r] + bb[r]);
        }
    }
}

// mix: rg[mt] = T2_tile x Amix^T   (vertex = lane c15, wave owns v-tile w)
DEVINL void do_mix(f32x4 (&rg)[8], const unsigned* Tlds, const unsigned* Amlds,
                   int w, int g, int c15)
{
    const int vrow = (w * 16 + c15) * TS + g * 4;
    u32x4 bf0 = *(const u32x4*)&Amlds[vrow];
    u32x4 bf1v = *(const u32x4*)&Amlds[vrow + 16];
    #pragma unroll
    for (int mt = 0; mt < 8; ++mt) {
        const int crow = TROW(mt * 16 + c15) + g * 4;
        u32x4 a0 = *(const u32x4*)&Tlds[crow];
        u32x4 a1 = *(const u32x4*)&Tlds[crow + 16];
        f32x4 a = {0.f, 0.f, 0.f, 0.f};
        a = MFMA(a0, bf0, a);
        a = MFMA(a1, bf1v, a);
        rg[mt] = a;
    }
}

// mix epilogue: LN (in-wave) + relu + residual -> Rf; optionally write H to LDS
DEVINL void mix_epi(const f32x4 (&rg)[8], float (&Rf)[8][4], unsigned* Hlds,
                    const float* gam, const float* bet, bool resid, bool writeH,
                    int w, int g, int c15)
{
    float s = 0.f, q = 0.f;
    #pragma unroll
    for (int mt = 0; mt < 8; ++mt)
        #pragma unroll
        for (int r = 0; r < 4; ++r) { float x = rg[mt][r]; s += x; q = fmaf(x, x, q); }
    s += __shfl_xor(s, 16); s += __shfl_xor(s, 32);
    q += __shfl_xor(q, 16); q += __shfl_xor(q, 32);
    const float m   = s * (1.f / 128.f);
    const float var = q * (1.f / 128.f) - m * m;
    const float rs  = rsqrtf(var + 1e-5f);
    const int v = w * 16 + c15;
    #pragma unroll
    for (int mt = 0; mt < 8; ++mt) {
        f32x4 gc = *(const f32x4*)&gam[mt * 16 + g * 4];
        f32x4 bc = *(const f32x4*)&bet[mt * 16 + g * 4];
        #pragma unroll
        for (int r = 0; r < 4; ++r) {
            float val = fmaxf((rg[mt][r] - m) * rs * gc[r] + bc[r], 0.f);
            if (resid) val += Rf[mt][r];
            Rf[mt][r] = val;
        }
        if (writeH) {
            u32x2 pr;
            pr[0] = pk2(Rf[mt][0], Rf[mt][1]);
            pr[1] = pk2(Rf[mt][2], Rf[mt][3]);
            *(u32x2*)&Hlds[v * HS + mt * 8 + g * 2] = pr;
        }
    }
}

// ---------------- kernel A ---------------------------------------------------
__global__ __launch_bounds__(256, 3) void gcn_mfma(
    const float* __restrict__ X, const float* __restrict__ A,
    const int* __restrict__ v1i, const int* __restrict__ v2i, const int* __restrict__ seat,
    const float* __restrict__ W0, const float* __restrict__ b0v,
    const float* __restrict__ g0v, const float* __restrict__ be0,
    const unsigned* __restrict__ W1G, const float* __restrict__ b1v,
    const float* __restrict__ g1v, const float* __restrict__ be1,
    const unsigned* __restrict__ W2G, const float* __restrict__ b2v,
    const float* __restrict__ g2v, const float* __restrict__ be2,
    const float* __restrict__ semb, float* __restrict__ hws, int spb)
{
    __shared__ unsigned Tlds[128 * TS + 4];  // 18.4KB (staggered rows)
    __shared__ unsigned Hlds[64 * HS];       // 17.4KB
    __shared__ unsigned Amlds[64 * TS];      // 9.2KB
    __shared__ float    PrmL[9][128];        // 4.6KB
    __shared__ float    Sm[4][128];          // 2KB
    __shared__ unsigned long long WpS[2];    // laundered W-frag pointers

    const int tid = threadIdx.x;
    const int l = tid & 63, w = tid >> 6, g = l >> 4, c15 = l & 15;

    if (tid < 128) {
        const int c = tid;
        PrmL[0][c] = b0v[c]; PrmL[1][c] = b1v[c]; PrmL[2][c] = b2v[c];
        PrmL[3][c] = g0v[c]; PrmL[4][c] = g1v[c]; PrmL[5][c] = g2v[c];
        PrmL[6][c] = be0[c]; PrmL[7][c] = be1[c]; PrmL[8][c] = be2[c];
    }
    if (tid == 0) {
        WpS[0] = (unsigned long long)W1G;
        WpS[1] = (unsigned long long)W2G;
    }
    for (int p = tid; p < 64 * TS; p += 256) {
        const int v = p / TS, uc = p % TS;
        unsigned val = 0u;
        if (v < 54 && uc < 27) {
            const int u = uc * 2;
            const float a0 = A[v * 54 + u];
            const float a1 = (u + 1 < 54) ? A[v * 54 + u + 1] : 0.f;
            val = pk2(a0, a1);
        }
        Amlds[p] = val;
    }

    // W0 fragments resident (8 VGPRs)
    u32x4 W0f[2];
    #pragma unroll
    for (int m2 = 0; m2 < 2; ++m2) {
        const int ch = (2 * w + m2) * 16 + c15;
        unsigned t0[4];
        #pragma unroll
        for (int jj = 0; jj < 4; ++jj) {
            const int k = g * 8 + 2 * jj;
            t0[jj] = (g < 2) ? pk2(W0[k * 128 + ch], W0[(k + 1) * 128 + ch]) : 0u;
        }
        W0f[m2] = (u32x4){t0[0], t0[1], t0[2], t0[3]};
    }
    __syncthreads();

    float Rf[8][4];
    f32x4 rg[8];     // unified conv/mix accumulators
    u32x4 wfp[8];    // prefetched W-fragments for the next conv phase

    // ---- prologue: conv0 of sample 0 ----
    conv0g(rg, X, blockIdx.x, W0f, g, c15);
    conv_epi(rg, (unsigned short*)Tlds, &PrmL[0][0], w, g, c15);
    __syncthreads();   // Tlds(s0) ready

    #pragma unroll 1
    for (int it = 0; it < spb; ++it) {
        const int n = blockIdx.x + gridDim.x * it;

        // laundered pointers -> loads reload from L2, never LICM'd into regs
        const u32x4* W1p = (const u32x4*)(((volatile unsigned long long*)WpS)[0]);
        const u32x4* W2p = (const u32x4*)(((volatile unsigned long long*)WpS)[1]);

        // ---- layer 0: mix of conv0 results; prefetch W1 under mix_epi ----
        do_mix(rg, Tlds, Amlds, w, g, c15);
        prefW(wfp, W1p, w, l);
        mix_epi(rg, Rf, Hlds, &PrmL[3][0], &PrmL[6][0], false, true, w, g, c15);
        __syncthreads();

        // ---- layer 1 ----
        conv12p(rg, Hlds, wfp, g, c15);
        conv_epi(rg, (unsigned short*)Tlds, &PrmL[1][0], w, g, c15);
        __syncthreads();
        do_mix(rg, Tlds, Amlds, w, g, c15);
        prefW(wfp, W2p, w, l);
        mix_epi(rg, Rf, Hlds, &PrmL[4][0], &PrmL[7][0], true, true, w, g, c15);
        __syncthreads();

        // ---- layer 2 (writes H to Hlds for the mean) ----
        conv12p(rg, Hlds, wfp, g, c15);
        conv_epi(rg, (unsigned short*)Tlds, &PrmL[2][0], w, g, c15);
        __syncthreads();
        do_mix(rg, Tlds, Amlds, w, g, c15);
        mix_epi(rg, Rf, Hlds, &PrmL[5][0], &PrmL[8][0], true, true, w, g, c15);
        __syncthreads();   // Hlds final ready; Tlds consumed

        // ---- MERGED PHASE: head(n) || conv0(n+1) -> one barrier ----
        const int v1 = v1i[n], v2 = v2i[n];
        int st = seat[n];
        st = st < 0 ? 0 : (st > 3 ? 3 : st);
        float* hr = hws + (size_t)n * HROW;
        const int v = w * 16 + c15;

        // v1/v2 gather from fp32 Rf (exact; before Rf is overwritten)
        if (v == v1 || v == v2) {
            #pragma unroll
            for (int mt = 0; mt < 8; ++mt) {
                f32x4 t;
                #pragma unroll
                for (int r = 0; r < 4; ++r) t[r] = Rf[mt][r];
                if (v == v1) *(f32x4*)&hr[mt * 16 + g * 4] = t;
                if (v == v2) *(f32x4*)&hr[128 + mt * 16 + g * 4] = t;
            }
        }

        // mean partials from Hlds: thread = (row-quarter w, ch-pair)
        {
            const int pair = tid & 63;
            const int nv = (w == 3) ? 6 : 16;   // rows 48..53 only in quarter 3
            float s0 = 0.f, s1 = 0.f;
            const unsigned* hb = &Hlds[(w * 16) * HS + pair];
            for (int r = 0; r < nv; ++r) {
                const unsigned u = hb[r * HS];
                s0 += __uint_as_float(u << 16);
                s1 += __uint_as_float(u & 0xffff0000u);
            }
            Sm[w][2 * pair]     = s0;
            Sm[w][2 * pair + 1] = s1;
        }
        if (tid < 8)       hr[384 + tid] = semb[st * 8 + tid];
        else if (tid < 16) hr[384 + tid] = 0.f;   // pad cols 392..399

        // conv0 of next sample (X load latency hides under head work above)
        if (it + 1 < spb) {
            conv0g(rg, X, n + (int)gridDim.x, W0f, g, c15);
            conv_epi(rg, (unsigned short*)Tlds, &PrmL[0][0], w, g, c15);
        }
        __syncthreads();   // Sm ready AND Tlds(n+1) ready — merged barrier

        if (tid < 128) {
            const float mn = (Sm[0][tid] + Sm[1][tid] + Sm[2][tid] + Sm[3][tid]) * (1.f / 54.f);
            hr[256 + tid] = mn;
        }
    }
}

// ---------------- weight frag init (runs once per launch, ~us) ---------------
__global__ void head_frag_init(const float* __restrict__ mW1,
                               const float* __restrict__ rW1,
                               const float* __restrict__ mW2,
                               const float* __restrict__ W1t,
                               const float* __restrict__ W2t,
                               unsigned* __restrict__ W1h, unsigned* __restrict__ W1l,
                               unsigned* __restrict__ R1h, unsigned* __restrict__ W2h,
                               unsigned* __restrict__ W1G, unsigned* __restrict__ W2G)
{
    const int t = blockIdx.x * 256 + threadIdx.x;
    if (t < 13 * 128 * 16) {
        const int j = t & 3, g = (t >> 2) & 3, col = (t >> 4) & 127, ks = t >> 11;
        const int k = ks * 32 + g * 8 + 2 * j;
        const float w0 = (k < 392)     ? mW1[k * 128 + col]       : 0.f;
        const float w1 = (k + 1 < 392) ? mW1[(k + 1) * 128 + col] : 0.f;
        const unsigned h0 = bfr(w0), h1 = bfr(w1);
        const float l0 = w0 - __uint_as_float(h0 << 16);
        const float l1 = w1 - __uint_as_float(h1 << 16);
        const int idx = ((ks * 8 + (col >> 4)) * 64 + g * 16 + (col & 15)) * 4 + j;
        W1h[idx] = h0 | (h1 << 16);
        W1l[idx] = pk2(l0, l1);
    }
    if (t < 13 * 64 * 16) {
        const int j = t & 3, g = (t >> 2) & 3, col = (t >> 4) & 63, ks = t >> 10;
        const int k = ks * 32 + g * 8 + 2 * j;
        const float w0 = (k < 392)     ? rW1[k * 64 + col]       : 0.f;
        const float w1 = (k + 1 < 392) ? rW1[(k + 1) * 64 + col] : 0.f;
        const int idx = ((ks * 4 + (col >> 4)) * 64 + g * 16 + (col & 15)) * 4 + j;
        R1h[idx] = pk2(w0, w1);
    }
    if (t < 4 * 64 * 16) {
        const int j = t & 3, g = (t >> 2) & 3, col = (t >> 4) & 63, ks2 = t >> 10;
        const int k = ks2 * 32 + g * 8 + 2 * j;
        const int idx = ((ks2 * 4 + (col >> 4)) * 64 + g * 16 + (col & 15)) * 4 + j;
        W2h[idx] = pk2(mW2[k * 64 + col], mW2[(k + 1) * 64 + col]);
    }
    // trunk conv W1/W2 A-fragments: idx = ((ct*4+ks)*64 + lane)*4 + j
    if (t < 8 * 4 * 64 * 4) {
        const int j = t & 3, lane = (t >> 2) & 63, ks = (t >> 8) & 3, ct = t >> 10;
        const int g2 = lane >> 4, c15 = lane & 15;
        const int k = ks * 32 + g2 * 8 + 2 * j;
        const int ch = ct * 16 + c15;
        W1G[t] = pk2(W1t[k * 128 + ch], W1t[(k + 1) * 128 + ch]);
        W2G[t] = pk2(W2t[k * 128 + ch], W2t[(k + 1) * 128 + ch]);
    }
}

// ---------------- kernel B: batched head, weights from global frags ----------
__global__ __launch_bounds__(256, 2) void head_mfma(
    const float* __restrict__ hws,
    const unsigned* __restrict__ W1hG, const unsigned* __restrict__ W1lG,
    const unsigned* __restrict__ R1hG, const unsigned* __restrict__ W2hG,
    const float* __restrict__ mb1, const float* __restrict__ mb2,
    const float* __restrict__ mW3, const float* __restrict__ mb3,
    const float* __restrict__ rb1, const float* __restrict__ rW2,
    const float* __restrict__ rb2,
    float* __restrict__ out, int N)
{
    __shared__ u32x4 Zh[16 * 64];         // 16KB

    const int tid = threadIdx.x, l = tid & 63, w = tid >> 6, g = l >> 4, c15 = l & 15;
    const int row = blockIdx.x * 64 + w * 16 + c15;

    const u32x4* W1h4 = (const u32x4*)W1hG;
    const u32x4* W1l4 = (const u32x4*)W1lG;
    const u32x4* R1h4 = (const u32x4*)R1hG;
    const u32x4* W2h4 = (const u32x4*)W2hG;

    f32x4 z1[8], rr[4];
    #pragma unroll
    for (int i = 0; i < 8; ++i) z1[i] = (f32x4){0.f, 0.f, 0.f, 0.f};
    #pragma unroll
    for (int i = 0; i < 4; ++i) rr[i] = (f32x4){0.f, 0.f, 0.f, 0.f};

    #pragma unroll 1
    for (int ks = 0; ks < 13; ++ks) {
        const float* hp = hws + (size_t)row * HROW + ks * 32 + g * 8;
        f32x4 f0 = *(const f32x4*)hp, f1 = *(const f32x4*)(hp + 4);
        float vv[8] = {f0[0], f0[1], f0[2], f0[3], f1[0], f1[1], f1[2], f1[3]};
        unsigned th[4], tl[4];
        #pragma unroll
        for (int jj = 0; jj < 4; ++jj) {
            unsigned ha = bfr(vv[2 * jj]), hb = bfr(vv[2 * jj + 1]);
            th[jj] = ha | (hb << 16);
            tl[jj] = pk2(vv[2 * jj] - __uint_as_float(ha << 16),
                         vv[2 * jj + 1] - __uint_as_float(hb << 16));
        }
        u32x4 ah = (u32x4){th[0], th[1], th[2], th[3]};
        u32x4 al = (u32x4){tl[0], tl[1], tl[2], tl[3]};
        #pragma unroll
        for (int nt = 0; nt < 8; ++nt) {
            u32x4 bh = W1h4[(ks * 8 + nt) * 64 + l];
            u32x4 bl = W1l4[(ks * 8 + nt) * 64 + l];
            f32x4 a = z1[nt];
            a = MFMA(ah, bh, a); a = MFMA(ah, bl, a); a = MFMA(al, bh, a);
            z1[nt] = a;
        }
        #pragma unroll
        for (int nt = 0; nt < 4; ++nt)
            rr[nt] = MFMA(ah, R1h4[(ks * 4 + nt) * 64 + l], rr[nt]);
    }

    float rp[4] = {0.f, 0.f, 0.f, 0.f};
    #pragma unroll
    for (int nt = 0; nt < 4; ++nt) {
        int c = nt * 16 + c15;
        float rb = rb1[c], rw = rW2[c];
        #pragma unroll
        for (int r = 0; r < 4; ++r) rp[r] += fmaxf(rr[nt][r] + rb, 0.f) * rw;
    }
    #pragma unroll
    for (int r = 0; r < 4; ++r) {
        float p = rp[r];
        #pragma unroll
        for (int m = 1; m <= 8; m <<= 1) p += __shfl_xor(p, m);
        if (c15 == 0) {
            int orow = blockIdx.x * 64 + w * 16 + g * 4 + r;
            out[N + orow] = 1.f / (1.f + expf(-(p + rb2[0])));
        }
    }

    {
        unsigned short* zp = (unsigned short*)Zh;
        #pragma unroll
        for (int nt = 0; nt < 8; ++nt) {
            int c = nt * 16 + c15;
            float bb = mb1[c];
            #pragma unroll
            for (int r = 0; r < 4; ++r) {
                float v = fmaxf(z1[nt][r] + bb, 0.f);
                int lanep = ((nt * 2 + (c15 >> 3)) & 3) * 16 + g * 4 + r;
                zp[((w * 4 + (nt >> 1)) * 64 + lanep) * 8 + (c15 & 7)] = (unsigned short)bfr(v);
            }
        }
    }
    __syncthreads();

    f32x4 z2a[4];
    #pragma unroll
    for (int i = 0; i < 4; ++i) z2a[i] = (f32x4){0.f, 0.f, 0.f, 0.f};
    #pragma unroll
    for (int ks2 = 0; ks2 < 4; ++ks2) {
        u32x4 za = Zh[(w * 4 + ks2) * 64 + l];
        #pragma unroll
        for (int nt2 = 0; nt2 < 4; ++nt2)
            z2a[nt2] = MFMA(za, W2h4[(ks2 * 4 + nt2) * 64 + l], z2a[nt2]);
    }
    float wp[4] = {0.f, 0.f, 0.f, 0.f};
    #pragma unroll
    for (int nt2 = 0; nt2 < 4; ++nt2) {
        int c = nt2 * 16 + c15;
        float bb = mb2[c], w3 = mW3[c];
        #pragma unroll
        for (int r = 0; r < 4; ++r) wp[r] += fmaxf(z2a[nt2][r] + bb, 0.f) * w3;
    }
    #pragma unroll
    for (int r = 0; r < 4; ++r) {
        float p = wp[r];
        #pragma unroll
        for (int m = 1; m <= 8; m <<= 1) p += __shfl_xor(p, m);
        if (c15 == 0) {
            int orow = blockIdx.x * 64 + w * 16 + g * 4 + r;
            out[orow] = p + mb3[0];
        }
    }
}

extern "C" void kernel_launch(void* const* d_in, const int* in_sizes, int n_in,
                              void* d_out, int out_size, void* d_ws, size_t ws_size,
                              hipStream_t stream) {
    const float* X        = (const float*)d_in[0];
    const float* A        = (const float*)d_in[1];
    const int*   v1_idx   = (const int*)d_in[2];
    const int*   v2_idx   = (const int*)d_in[3];
    const int*   seat     = (const int*)d_in[4];
    const float* W0       = (const float*)d_in[5];
    const float* b0       = (const float*)d_in[6];
    const float* g0       = (const float*)d_in[7];
    const float* be0      = (const float*)d_in[8];
    const float* W1       = (const float*)d_in[9];
    const float* b1       = (const float*)d_in[10];
    const float* g1       = (const float*)d_in[11];
    const float* be1      = (const float*)d_in[12];
    const float* W2       = (const float*)d_in[13];
    const float* b2       = (const float*)d_in[14];
    const float* g2       = (const float*)d_in[15];
    const float* be2      = (const float*)d_in[16];
    const float* seat_emb = (const float*)d_in[17];
    const float* mW1      = (const float*)d_in[18];
    const float* mb1      = (const float*)d_in[19];
    const float* mW2      = (const float*)d_in[20];
    const float* mb2      = (const float*)d_in[21];
    const float* mW3      = (const float*)d_in[22];
    const float* mb3      = (const float*)d_in[23];
    const float* rW1      = (const float*)d_in[24];
    const float* rb1      = (const float*)d_in[25];
    const float* rW2      = (const float*)d_in[26];
    const float* rb2      = (const float*)d_in[27];

    const int N = in_sizes[2];           // 16384
    float* out = (float*)d_out;

    // ws layout: hws [N][400] fp32 | W1h | W1l | R1h | W2h | W1G | W2G
    float*    hws = (float*)d_ws;
    unsigned* W1h = (unsigned*)((char*)d_ws + (size_t)N * HROW * 4);
    unsigned* W1l = W1h + 26624;
    unsigned* R1h = W1l + 26624;
    unsigned* W2h = R1h + 13312;
    unsigned* W1G = W2h + 4096;
    unsigned* W2G = W1G + 8192;          // total ~26.56MB (< proven 27.3MB)

    head_frag_init<<<104, 256, 0, stream>>>(mW1, rW1, mW2, W1, W2,
                                            W1h, W1l, R1h, W2h, W1G, W2G);

    const int spb = 8;
    const int gridA = N / spb;           // 2048
    gcn_mfma<<<gridA, 256, 0, stream>>>(
        X, A, v1_idx, v2_idx, seat,
        W0, b0, g0, be0, W1G, b1, g1, be1, W2G, b2, g2, be2,
        seat_emb, hws, spb);

    const int gridB = N / 64;            // 256
    head_mfma<<<gridB, 256, 0, stream>>>(
        hws, W1h, W1l, R1h, W2h,
        mb1, mb2, mW3, mb3, rb1, rW2, rb2, out, N);
}

// Round 17
// 334.100 us; speedup vs baseline: 1.0097x; 1.0097x over previous
//
#include <hip/hip_runtime.h>
#include <hip/hip_bf16.h>
#include <math.h>

// ---------------------------------------------------------------------------
// R17 = R15 (best, 323.7us: merged head||conv0 phase, 6 barriers/sample,
//   reg-resident Rf, W-frags streamed from L2, (256,3), no spill)
//   + grid quantization fix: spb 8 -> 2 (grid 2048 -> 8192 blocks).
//   Capacity = 768 co-resident blocks; 2048 = 2.67 generations -> ~11% drain
//   tail. 8192 blocks -> ~3% tail, at the cost of 4x prologues (~1-2us each
//   vs ~30us block) ≈ +3-4%. Net predicted +4-7%.
// R16 post-mortem: W-frag prefetch (+32 regs) re-spilled (WRITE 38->63MB) —
//   reverted; register headroom at (256,3) is ZERO.
// ---------------------------------------------------------------------------

typedef __bf16 bf16x8 __attribute__((ext_vector_type(8)));
typedef float  f32x4  __attribute__((ext_vector_type(4)));
typedef unsigned int u32x4 __attribute__((ext_vector_type(4)));
typedef unsigned int u32x2 __attribute__((ext_vector_type(2)));

#define DEVINL __device__ __forceinline__
#define HROW 400   // hws row stride (floats); cols 392..399 zero-padded

DEVINL unsigned bfr(float x) {             // float -> bf16 bits (RNE) — cold paths
    unsigned u = __float_as_uint(x);
    return (u + 0x7fffu + ((u >> 16) & 1u)) >> 16;
}
DEVINL unsigned pk2(float a, float b) {    // v_cvt_pk_bf16_f32
    float2 f; f.x = a; f.y = b;
    __hip_bfloat162 h = __float22bfloat162_rn(f);
    unsigned u;
    __builtin_memcpy(&u, &h, sizeof(u));
    return u;
}
DEVINL unsigned short bf1(float x) {       // single f32 -> bf16: 1 cvt_pk inst
    return (unsigned short)pk2(x, x);
}

DEVINL f32x4 MFMA(u32x4 a, u32x4 b, f32x4 c) {
    return __builtin_amdgcn_mfma_f32_16x16x32_bf16(
        __builtin_bit_cast(bf16x8, a), __builtin_bit_cast(bf16x8, b), c, 0, 0, 0);
}

#define TS 36   // Tlds / Amlds row stride in u32 (pairs of bf16)
#define HS 68   // Hlds row stride in u32
// staggered Tlds row base (dwords)
DEVINL int TROW(int r) { return r * TS + ((r >> 3) & 1) * 4; }

// conv layers 1,2: rg[m2*4+ut] = (W^T)_tile x H-as-B, W-frags from global (L2)
DEVINL void conv12g(f32x4 (&rg)[8], const unsigned* Hlds,
                    const u32x4* __restrict__ Wp, int w, int g, int c15, int l)
{
    #pragma unroll
    for (int i = 0; i < 8; ++i) rg[i] = (f32x4){0.f, 0.f, 0.f, 0.f};
    #pragma unroll
    for (int ks = 0; ks < 4; ++ks) {
        u32x4 wf0 = Wp[((2 * w + 0) * 4 + ks) * 64 + l];
        u32x4 wf1 = Wp[((2 * w + 1) * 4 + ks) * 64 + l];
        u32x4 hb[4];
        #pragma unroll
        for (int ut = 0; ut < 4; ++ut)
            hb[ut] = *(const u32x4*)&Hlds[(ut * 16 + c15) * HS + ks * 16 + g * 4];
        #pragma unroll
        for (int ut = 0; ut < 4; ++ut) {
            rg[ut]     = MFMA(wf0, hb[ut], rg[ut]);
            rg[4 + ut] = MFMA(wf1, hb[ut], rg[4 + ut]);
        }
    }
}

// conv0: X (global) -> bf16 A-frags -> rg (K=16 zero-padded to 32)
DEVINL void conv0g(f32x4 (&rg)[8], const float* __restrict__ X, int n,
                   const u32x4 (&W0f)[2], int g, int c15)
{
    #pragma unroll
    for (int i = 0; i < 8; ++i) rg[i] = (f32x4){0.f, 0.f, 0.f, 0.f};
    #pragma unroll
    for (int ut = 0; ut < 4; ++ut) {
        const int u = ut * 16 + c15;
        u32x4 xb = (u32x4){0u, 0u, 0u, 0u};
        if (g < 2 && u < 54) {
            const f32x4* xp = (const f32x4*)(X + (size_t)n * 864 + u * 16 + g * 8);
            f32x4 f0 = xp[0], f1 = xp[1];
            xb = (u32x4){pk2(f0[0], f0[1]), pk2(f0[2], f0[3]),
                         pk2(f1[0], f1[1]), pk2(f1[2], f1[3])};
        }
        rg[ut]     = MFMA(W0f[0], xb, rg[ut]);
        rg[4 + ut] = MFMA(W0f[1], xb, rg[4 + ut]);
    }
}

// conv epilogue: rg + bias -> Tlds (staggered rows), direct b16 scatter
DEVINL void conv_epi(const f32x4 (&rg)[8], unsigned short* TldsH, const float* bias,
                     int w, int g, int c15)
{
    #pragma unroll
    for (int m2 = 0; m2 < 2; ++m2) {
        const int chb = (2 * w + m2) * 16;
        f32x4 bb = *(const f32x4*)&bias[chb + g * 4];
        #pragma unroll
        for (int ut = 0; ut < 4; ++ut) {
            const int u = ut * 16 + c15;
            #pragma unroll
            for (int r = 0; r < 4; ++r)
                TldsH[TROW(chb + g * 4 + r) * 2 + u] = bf1(rg[m2 * 4 + ut][r] + bb[r]);
        }
    }
}

// mix: rg[mt] = T2_tile x Amix^T   (vertex = lane c15, wave owns v-tile w)
DEVINL void do_mix(f32x4 (&rg)[8], const unsigned* Tlds, const unsigned* Amlds,
                   int w, int g, int c15)
{
    const int vrow = (w * 16 + c15) * TS + g * 4;
    u32x4 bf0 = *(const u32x4*)&Amlds[vrow];
    u32x4 bf1v = *(const u32x4*)&Amlds[vrow + 16];
    #pragma unroll
    for (int mt = 0; mt < 8; ++mt) {
        const int crow = TROW(mt * 16 + c15) + g * 4;
        u32x4 a0 = *(const u32x4*)&Tlds[crow];
        u32x4 a1 = *(const u32x4*)&Tlds[crow + 16];
        f32x4 a = {0.f, 0.f, 0.f, 0.f};
        a = MFMA(a0, bf0, a);
        a = MFMA(a1, bf1v, a);
        rg[mt] = a;
    }
}

// mix epilogue: LN (in-wave) + relu + residual -> Rf; optionally write H to LDS
DEVINL void mix_epi(const f32x4 (&rg)[8], float (&Rf)[8][4], unsigned* Hlds,
                    const float* gam, const float* bet, bool resid, bool writeH,
                    int w, int g, int c15)
{
    float s = 0.f, q = 0.f;
    #pragma unroll
    for (int mt = 0; mt < 8; ++mt)
        #pragma unroll
        for (int r = 0; r < 4; ++r) { float x = rg[mt][r]; s += x; q = fmaf(x, x, q); }
    s += __shfl_xor(s, 16); s += __shfl_xor(s, 32);
    q += __shfl_xor(q, 16); q += __shfl_xor(q, 32);
    const float m   = s * (1.f / 128.f);
    const float var = q * (1.f / 128.f) - m * m;
    const float rs  = rsqrtf(var + 1e-5f);
    const int v = w * 16 + c15;
    #pragma unroll
    for (int mt = 0; mt < 8; ++mt) {
        f32x4 gc = *(const f32x4*)&gam[mt * 16 + g * 4];
        f32x4 bc = *(const f32x4*)&bet[mt * 16 + g * 4];
        #pragma unroll
        for (int r = 0; r < 4; ++r) {
            float val = fmaxf((rg[mt][r] - m) * rs * gc[r] + bc[r], 0.f);
            if (resid) val += Rf[mt][r];
            Rf[mt][r] = val;
        }
        if (writeH) {
            u32x2 pr;
            pr[0] = pk2(Rf[mt][0], Rf[mt][1]);
            pr[1] = pk2(Rf[mt][2], Rf[mt][3]);
            *(u32x2*)&Hlds[v * HS + mt * 8 + g * 2] = pr;
        }
    }
}

// ---------------- kernel A ---------------------------------------------------
__global__ __launch_bounds__(256, 3) void gcn_mfma(
    const float* __restrict__ X, const float* __restrict__ A,
    const int* __restrict__ v1i, const int* __restrict__ v2i, const int* __restrict__ seat,
    const float* __restrict__ W0, const float* __restrict__ b0v,
    const float* __restrict__ g0v, const float* __restrict__ be0,
    const unsigned* __restrict__ W1G, const float* __restrict__ b1v,
    const float* __restrict__ g1v, const float* __restrict__ be1,
    const unsigned* __restrict__ W2G, const float* __restrict__ b2v,
    const float* __restrict__ g2v, const float* __restrict__ be2,
    const float* __restrict__ semb, float* __restrict__ hws, int spb)
{
    __shared__ unsigned Tlds[128 * TS + 4];  // 18.4KB (staggered rows)
    __shared__ unsigned Hlds[64 * HS];       // 17.4KB
    __shared__ unsigned Amlds[64 * TS];      // 9.2KB
    __shared__ float    PrmL[9][128];        // 4.6KB
    __shared__ float    Sm[4][128];          // 2KB
    __shared__ unsigned long long WpS[2];    // laundered W-frag pointers

    const int tid = threadIdx.x;
    const int l = tid & 63, w = tid >> 6, g = l >> 4, c15 = l & 15;

    if (tid < 128) {
        const int c = tid;
        PrmL[0][c] = b0v[c]; PrmL[1][c] = b1v[c]; PrmL[2][c] = b2v[c];
        PrmL[3][c] = g0v[c]; PrmL[4][c] = g1v[c]; PrmL[5][c] = g2v[c];
        PrmL[6][c] = be0[c]; PrmL[7][c] = be1[c]; PrmL[8][c] = be2[c];
    }
    if (tid == 0) {
        WpS[0] = (unsigned long long)W1G;
        WpS[1] = (unsigned long long)W2G;
    }
    for (int p = tid; p < 64 * TS; p += 256) {
        const int v = p / TS, uc = p % TS;
        unsigned val = 0u;
        if (v < 54 && uc < 27) {
            const int u = uc * 2;
            const float a0 = A[v * 54 + u];
            const float a1 = (u + 1 < 54) ? A[v * 54 + u + 1] : 0.f;
            val = pk2(a0, a1);
        }
        Amlds[p] = val;
    }

    // W0 fragments resident (8 VGPRs)
    u32x4 W0f[2];
    #pragma unroll
    for (int m2 = 0; m2 < 2; ++m2) {
        const int ch = (2 * w + m2) * 16 + c15;
        unsigned t0[4];
        #pragma unroll
        for (int jj = 0; jj < 4; ++jj) {
            const int k = g * 8 + 2 * jj;
            t0[jj] = (g < 2) ? pk2(W0[k * 128 + ch], W0[(k + 1) * 128 + ch]) : 0u;
        }
        W0f[m2] = (u32x4){t0[0], t0[1], t0[2], t0[3]};
    }
    __syncthreads();

    float Rf[8][4];
    f32x4 rg[8];     // unified conv/mix accumulators

    // ---- prologue: conv0 of sample 0 ----
    conv0g(rg, X, blockIdx.x, W0f, g, c15);
    conv_epi(rg, (unsigned short*)Tlds, &PrmL[0][0], w, g, c15);
    __syncthreads();   // Tlds(s0) ready

    #pragma unroll 1
    for (int it = 0; it < spb; ++it) {
        const int n = blockIdx.x + gridDim.x * it;

        // laundered pointers -> loads reload from L2, never LICM'd into regs
        const u32x4* W1p = (const u32x4*)(((volatile unsigned long long*)WpS)[0]);
        const u32x4* W2p = (const u32x4*)(((volatile unsigned long long*)WpS)[1]);

        // ---- layer 0: mix of conv0 results ----
        do_mix(rg, Tlds, Amlds, w, g, c15);
        mix_epi(rg, Rf, Hlds, &PrmL[3][0], &PrmL[6][0], false, true, w, g, c15);
        __syncthreads();

        // ---- layer 1 ----
        conv12g(rg, Hlds, W1p, w, g, c15, l);
        conv_epi(rg, (unsigned short*)Tlds, &PrmL[1][0], w, g, c15);
        __syncthreads();
        do_mix(rg, Tlds, Amlds, w, g, c15);
        mix_epi(rg, Rf, Hlds, &PrmL[4][0], &PrmL[7][0], true, true, w, g, c15);
        __syncthreads();

        // ---- layer 2 (writes H to Hlds for the mean) ----
        conv12g(rg, Hlds, W2p, w, g, c15, l);
        conv_epi(rg, (unsigned short*)Tlds, &PrmL[2][0], w, g, c15);
        __syncthreads();
        do_mix(rg, Tlds, Amlds, w, g, c15);
        mix_epi(rg, Rf, Hlds, &PrmL[5][0], &PrmL[8][0], true, true, w, g, c15);
        __syncthreads();   // Hlds final ready; Tlds consumed

        // ---- MERGED PHASE: head(n) || conv0(n+1) -> one barrier ----
        const int v1 = v1i[n], v2 = v2i[n];
        int st = seat[n];
        st = st < 0 ? 0 : (st > 3 ? 3 : st);
        float* hr = hws + (size_t)n * HROW;
        const int v = w * 16 + c15;

        // v1/v2 gather from fp32 Rf (exact; before Rf is overwritten)
        if (v == v1 || v == v2) {
            #pragma unroll
            for (int mt = 0; mt < 8; ++mt) {
                f32x4 t;
                #pragma unroll
                for (int r = 0; r < 4; ++r) t[r] = Rf[mt][r];
                if (v == v1) *(f32x4*)&hr[mt * 16 + g * 4] = t;
                if (v == v2) *(f32x4*)&hr[128 + mt * 16 + g * 4] = t;
            }
        }

        // mean partials from Hlds: thread = (row-quarter w, ch-pair)
        {
            const int pair = tid & 63;
            const int nv = (w == 3) ? 6 : 16;   // rows 48..53 only in quarter 3
            float s0 = 0.f, s1 = 0.f;
            const unsigned* hb = &Hlds[(w * 16) * HS + pair];
            for (int r = 0; r < nv; ++r) {
                const unsigned u = hb[r * HS];
                s0 += __uint_as_float(u << 16);
                s1 += __uint_as_float(u & 0xffff0000u);
            }
            Sm[w][2 * pair]     = s0;
            Sm[w][2 * pair + 1] = s1;
        }
        if (tid < 8)       hr[384 + tid] = semb[st * 8 + tid];
        else if (tid < 16) hr[384 + tid] = 0.f;   // pad cols 392..399

        // conv0 of next sample (X load latency hides under head work above)
        if (it + 1 < spb) {
            conv0g(rg, X, n + (int)gridDim.x, W0f, g, c15);
            conv_epi(rg, (unsigned short*)Tlds, &PrmL[0][0], w, g, c15);
        }
        __syncthreads();   // Sm ready AND Tlds(n+1) ready — merged barrier

        if (tid < 128) {
            const float mn = (Sm[0][tid] + Sm[1][tid] + Sm[2][tid] + Sm[3][tid]) * (1.f / 54.f);
            hr[256 + tid] = mn;
        }
    }
}

// ---------------- weight frag init (runs once per launch, ~us) ---------------
__global__ void head_frag_init(const float* __restrict__ mW1,
                               const float* __restrict__ rW1,
                               const float* __restrict__ mW2,
                               const float* __restrict__ W1t,
                               const float* __restrict__ W2t,
                               unsigned* __restrict__ W1h, unsigned* __restrict__ W1l,
                               unsigned* __restrict__ R1h, unsigned* __restrict__ W2h,
                               unsigned* __restrict__ W1G, unsigned* __restrict__ W2G)
{
    const int t = blockIdx.x * 256 + threadIdx.x;
    if (t < 13 * 128 * 16) {
        const int j = t & 3, g = (t >> 2) & 3, col = (t >> 4) & 127, ks = t >> 11;
        const int k = ks * 32 + g * 8 + 2 * j;
        const float w0 = (k < 392)     ? mW1[k * 128 + col]       : 0.f;
        const float w1 = (k + 1 < 392) ? mW1[(k + 1) * 128 + col] : 0.f;
        const unsigned h0 = bfr(w0), h1 = bfr(w1);
        const float l0 = w0 - __uint_as_float(h0 << 16);
        const float l1 = w1 - __uint_as_float(h1 << 16);
        const int idx = ((ks * 8 + (col >> 4)) * 64 + g * 16 + (col & 15)) * 4 + j;
        W1h[idx] = h0 | (h1 << 16);
        W1l[idx] = pk2(l0, l1);
    }
    if (t < 13 * 64 * 16) {
        const int j = t & 3, g = (t >> 2) & 3, col = (t >> 4) & 63, ks = t >> 10;
        const int k = ks * 32 + g * 8 + 2 * j;
        const float w0 = (k < 392)     ? rW1[k * 64 + col]       : 0.f;
        const float w1 = (k + 1 < 392) ? rW1[(k + 1) * 64 + col] : 0.f;
        const int idx = ((ks * 4 + (col >> 4)) * 64 + g * 16 + (col & 15)) * 4 + j;
        R1h[idx] = pk2(w0, w1);
    }
    if (t < 4 * 64 * 16) {
        const int j = t & 3, g = (t >> 2) & 3, col = (t >> 4) & 63, ks2 = t >> 10;
        const int k = ks2 * 32 + g * 8 + 2 * j;
        const int idx = ((ks2 * 4 + (col >> 4)) * 64 + g * 16 + (col & 15)) * 4 + j;
        W2h[idx] = pk2(mW2[k * 64 + col], mW2[(k + 1) * 64 + col]);
    }
    // trunk conv W1/W2 A-fragments: idx = ((ct*4+ks)*64 + lane)*4 + j
    if (t < 8 * 4 * 64 * 4) {
        const int j = t & 3, lane = (t >> 2) & 63, ks = (t >> 8) & 3, ct = t >> 10;
        const int g2 = lane >> 4, c15 = lane & 15;
        const int k = ks * 32 + g2 * 8 + 2 * j;
        const int ch = ct * 16 + c15;
        W1G[t] = pk2(W1t[k * 128 + ch], W1t[(k + 1) * 128 + ch]);
        W2G[t] = pk2(W2t[k * 128 + ch], W2t[(k + 1) * 128 + ch]);
    }
}

// ---------------- kernel B: batched head, weights from global frags ----------
__global__ __launch_bounds__(256, 2) void head_mfma(
    const float* __restrict__ hws,
    const unsigned* __restrict__ W1hG, const unsigned* __restrict__ W1lG,
    const unsigned* __restrict__ R1hG, const unsigned* __restrict__ W2hG,
    const float* __restrict__ mb1, const float* __restrict__ mb2,
    const float* __restrict__ mW3, const float* __restrict__ mb3,
    const float* __restrict__ rb1, const float* __restrict__ rW2,
    const float* __restrict__ rb2,
    float* __restrict__ out, int N)
{
    __shared__ u32x4 Zh[16 * 64];         // 16KB

    const int tid = threadIdx.x, l = tid & 63, w = tid >> 6, g = l >> 4, c15 = l & 15;
    const int row = blockIdx.x * 64 + w * 16 + c15;

    const u32x4* W1h4 = (const u32x4*)W1hG;
    const u32x4* W1l4 = (const u32x4*)W1lG;
    const u32x4* R1h4 = (const u32x4*)R1hG;
    const u32x4* W2h4 = (const u32x4*)W2hG;

    f32x4 z1[8], rr[4];
    #pragma unroll
    for (int i = 0; i < 8; ++i) z1[i] = (f32x4){0.f, 0.f, 0.f, 0.f};
    #pragma unroll
    for (int i = 0; i < 4; ++i) rr[i] = (f32x4){0.f, 0.f, 0.f, 0.f};

    #pragma unroll 1
    for (int ks = 0; ks < 13; ++ks) {
        const float* hp = hws + (size_t)row * HROW + ks * 32 + g * 8;
        f32x4 f0 = *(const f32x4*)hp, f1 = *(const f32x4*)(hp + 4);
        float vv[8] = {f0[0], f0[1], f0[2], f0[3], f1[0], f1[1], f1[2], f1[3]};
        unsigned th[4], tl[4];
        #pragma unroll
        for (int jj = 0; jj < 4; ++jj) {
            unsigned ha = bfr(vv[2 * jj]), hb = bfr(vv[2 * jj + 1]);
            th[jj] = ha | (hb << 16);
            tl[jj] = pk2(vv[2 * jj] - __uint_as_float(ha << 16),
                         vv[2 * jj + 1] - __uint_as_float(hb << 16));
        }
        u32x4 ah = (u32x4){th[0], th[1], th[2], th[3]};
        u32x4 al = (u32x4){tl[0], tl[1], tl[2], tl[3]};
        #pragma unroll
        for (int nt = 0; nt < 8; ++nt) {
            u32x4 bh = W1h4[(ks * 8 + nt) * 64 + l];
            u32x4 bl = W1l4[(ks * 8 + nt) * 64 + l];
            f32x4 a = z1[nt];
            a = MFMA(ah, bh, a); a = MFMA(ah, bl, a); a = MFMA(al, bh, a);
            z1[nt] = a;
        }
        #pragma unroll
        for (int nt = 0; nt < 4; ++nt)
            rr[nt] = MFMA(ah, R1h4[(ks * 4 + nt) * 64 + l], rr[nt]);
    }

    float rp[4] = {0.f, 0.f, 0.f, 0.f};
    #pragma unroll
    for (int nt = 0; nt < 4; ++nt) {
        int c = nt * 16 + c15;
        float rb = rb1[c], rw = rW2[c];
        #pragma unroll
        for (int r = 0; r < 4; ++r) rp[r] += fmaxf(rr[nt][r] + rb, 0.f) * rw;
    }
    #pragma unroll
    for (int r = 0; r < 4; ++r) {
        float p = rp[r];
        #pragma unroll
        for (int m = 1; m <= 8; m <<= 1) p += __shfl_xor(p, m);
        if (c15 == 0) {
            int orow = blockIdx.x * 64 + w * 16 + g * 4 + r;
            out[N + orow] = 1.f / (1.f + expf(-(p + rb2[0])));
        }
    }

    {
        unsigned short* zp = (unsigned short*)Zh;
        #pragma unroll
        for (int nt = 0; nt < 8; ++nt) {
            int c = nt * 16 + c15;
            float bb = mb1[c];
            #pragma unroll
            for (int r = 0; r < 4; ++r) {
                float v = fmaxf(z1[nt][r] + bb, 0.f);
                int lanep = ((nt * 2 + (c15 >> 3)) & 3) * 16 + g * 4 + r;
                zp[((w * 4 + (nt >> 1)) * 64 + lanep) * 8 + (c15 & 7)] = (unsigned short)bfr(v);
            }
        }
    }
    __syncthreads();

    f32x4 z2a[4];
    #pragma unroll
    for (int i = 0; i < 4; ++i) z2a[i] = (f32x4){0.f, 0.f, 0.f, 0.f};
    #pragma unroll
    for (int ks2 = 0; ks2 < 4; ++ks2) {
        u32x4 za = Zh[(w * 4 + ks2) * 64 + l];
        #pragma unroll
        for (int nt2 = 0; nt2 < 4; ++nt2)
            z2a[nt2] = MFMA(za, W2h4[(ks2 * 4 + nt2) * 64 + l], z2a[nt2]);
    }
    float wp[4] = {0.f, 0.f, 0.f, 0.f};
    #pragma unroll
    for (int nt2 = 0; nt2 < 4; ++nt2) {
        int c = nt2 * 16 + c15;
        float bb = mb2[c], w3 = mW3[c];
        #pragma unroll
        for (int r = 0; r < 4; ++r) wp[r] += fmaxf(z2a[nt2][r] + bb, 0.f) * w3;
    }
    #pragma unroll
    for (int r = 0; r < 4; ++r) {
        float p = wp[r];
        #pragma unroll
        for (int m = 1; m <= 8; m <<= 1) p += __shfl_xor(p, m);
        if (c15 == 0) {
            int orow = blockIdx.x * 64 + w * 16 + g * 4 + r;
            out[orow] = p + mb3[0];
        }
    }
}

extern "C" void kernel_launch(void* const* d_in, const int* in_sizes, int n_in,
                              void* d_out, int out_size, void* d_ws, size_t ws_size,
                              hipStream_t stream) {
    const float* X        = (const float*)d_in[0];
    const float* A        = (const float*)d_in[1];
    const int*   v1_idx   = (const int*)d_in[2];
    const int*   v2_idx   = (const int*)d_in[3];
    const int*   seat     = (const int*)d_in[4];
    const float* W0       = (const float*)d_in[5];
    const float* b0       = (const float*)d_in[6];
    const float* g0       = (const float*)d_in[7];
    const float* be0      = (const float*)d_in[8];
    const float* W1       = (const float*)d_in[9];
    const float* b1       = (const float*)d_in[10];
    const float* g1       = (const float*)d_in[11];
    const float* be1      = (const float*)d_in[12];
    const float* W2       = (const float*)d_in[13];
    const float* b2       = (const float*)d_in[14];
    const float* g2       = (const float*)d_in[15];
    const float* be2      = (const float*)d_in[16];
    const float* seat_emb = (const float*)d_in[17];
    const float* mW1      = (const float*)d_in[18];
    const float* mb1      = (const float*)d_in[19];
    const float* mW2      = (const float*)d_in[20];
    const float* mb2      = (const float*)d_in[21];
    const float* mW3      = (const float*)d_in[22];
    const float* mb3      = (const float*)d_in[23];
    const float* rW1      = (const float*)d_in[24];
    const float* rb1      = (const float*)d_in[25];
    const float* rW2      = (const float*)d_in[26];
    const float* rb2      = (const float*)d_in[27];

    const int N = in_sizes[2];           // 16384
    float* out = (float*)d_out;

    // ws layout: hws [N][400] fp32 | W1h | W1l | R1h | W2h | W1G | W2G
    float*    hws = (float*)d_ws;
    unsigned* W1h = (unsigned*)((char*)d_ws + (size_t)N * HROW * 4);
    unsigned* W1l = W1h + 26624;
    unsigned* R1h = W1l + 26624;
    unsigned* W2h = R1h + 13312;
    unsigned* W1G = W2h + 4096;
    unsigned* W2G = W1G + 8192;          // total ~26.56MB (< proven 27.3MB)

    head_frag_init<<<104, 256, 0, stream>>>(mW1, rW1, mW2, W1, W2,
                                            W1h, W1l, R1h, W2h, W1G, W2G);

    const int spb = 2;
    const int gridA = N / spb;           // 8192 blocks: tail waste 11% -> 3%
    gcn_mfma<<<gridA, 256, 0, stream>>>(
        X, A, v1_idx, v2_idx, seat,
        W0, b0, g0, be0, W1G, b1, g1, be1, W2G, b2, g2, be2,
        seat_emb, hws, spb);

    const int gridB = N / 64;            // 256
    head_mfma<<<gridB, 256, 0, stream>>>(
        hws, W1h, W1l, R1h, W2h,
        mb1, mb2, mW3, mb3, rb1, rW2, rb2, out, N);
}

// Round 18
// 322.755 us; speedup vs baseline: 1.0452x; 1.0352x over previous
//
#include <hip/hip_runtime.h>
#include <hip/hip_bf16.h>
#include <math.h>

// ---------------------------------------------------------------------------
// R18 = exact revert to R15 (best verified: 323.7us, 7.98x over baseline).
//   Design: fused bf16-MFMA trunk (transposed world), merged head||conv0
//   phase (6 barriers/sample), reg-resident Rf residual, W1/W2 frags streamed
//   from L2 via laundered pointers, (256,3), spb=8, batched split-bf16 head.
// Ledger of exhausted levers (R11-R17): zero reg headroom at (256,3);
//   4 blk/CU trades worse; 6 barriers structural; bank-conflict counter is
//   b128 structural overhead; grid 2048 optimal. Counters show structural
//   plateau (VALU 49 / MFMA 17.5 / HBM 3%), not a hardware roofline —
//   breaking it needs a ground-up wave-desynchronized pipeline.
// ---------------------------------------------------------------------------

typedef __bf16 bf16x8 __attribute__((ext_vector_type(8)));
typedef float  f32x4  __attribute__((ext_vector_type(4)));
typedef unsigned int u32x4 __attribute__((ext_vector_type(4)));
typedef unsigned int u32x2 __attribute__((ext_vector_type(2)));

#define DEVINL __device__ __forceinline__
#define HROW 400   // hws row stride (floats); cols 392..399 zero-padded

DEVINL unsigned bfr(float x) {             // float -> bf16 bits (RNE) — cold paths
    unsigned u = __float_as_uint(x);
    return (u + 0x7fffu + ((u >> 16) & 1u)) >> 16;
}
DEVINL unsigned pk2(float a, float b) {    // v_cvt_pk_bf16_f32
    float2 f; f.x = a; f.y = b;
    __hip_bfloat162 h = __float22bfloat162_rn(f);
    unsigned u;
    __builtin_memcpy(&u, &h, sizeof(u));
    return u;
}
DEVINL unsigned short bf1(float x) {       // single f32 -> bf16: 1 cvt_pk inst
    return (unsigned short)pk2(x, x);
}

DEVINL f32x4 MFMA(u32x4 a, u32x4 b, f32x4 c) {
    return __builtin_amdgcn_mfma_f32_16x16x32_bf16(
        __builtin_bit_cast(bf16x8, a), __builtin_bit_cast(bf16x8, b), c, 0, 0, 0);
}

#define TS 36   // Tlds / Amlds row stride in u32 (pairs of bf16)
#define HS 68   // Hlds row stride in u32
// staggered Tlds row base (dwords)
DEVINL int TROW(int r) { return r * TS + ((r >> 3) & 1) * 4; }

// conv layers 1,2: rg[m2*4+ut] = (W^T)_tile x H-as-B, W-frags from global (L2)
DEVINL void conv12g(f32x4 (&rg)[8], const unsigned* Hlds,
                    const u32x4* __restrict__ Wp, int w, int g, int c15, int l)
{
    #pragma unroll
    for (int i = 0; i < 8; ++i) rg[i] = (f32x4){0.f, 0.f, 0.f, 0.f};
    #pragma unroll
    for (int ks = 0; ks < 4; ++ks) {
        u32x4 wf0 = Wp[((2 * w + 0) * 4 + ks) * 64 + l];
        u32x4 wf1 = Wp[((2 * w + 1) * 4 + ks) * 64 + l];
        u32x4 hb[4];
        #pragma unroll
        for (int ut = 0; ut < 4; ++ut)
            hb[ut] = *(const u32x4*)&Hlds[(ut * 16 + c15) * HS + ks * 16 + g * 4];
        #pragma unroll
        for (int ut = 0; ut < 4; ++ut) {
            rg[ut]     = MFMA(wf0, hb[ut], rg[ut]);
            rg[4 + ut] = MFMA(wf1, hb[ut], rg[4 + ut]);
        }
    }
}

// conv0: X (global) -> bf16 A-frags -> rg (K=16 zero-padded to 32)
DEVINL void conv0g(f32x4 (&rg)[8], const float* __restrict__ X, int n,
                   const u32x4 (&W0f)[2], int g, int c15)
{
    #pragma unroll
    for (int i = 0; i < 8; ++i) rg[i] = (f32x4){0.f, 0.f, 0.f, 0.f};
    #pragma unroll
    for (int ut = 0; ut < 4; ++ut) {
        const int u = ut * 16 + c15;
        u32x4 xb = (u32x4){0u, 0u, 0u, 0u};
        if (g < 2 && u < 54) {
            const f32x4* xp = (const f32x4*)(X + (size_t)n * 864 + u * 16 + g * 8);
            f32x4 f0 = xp[0], f1 = xp[1];
            xb = (u32x4){pk2(f0[0], f0[1]), pk2(f0[2], f0[3]),
                         pk2(f1[0], f1[1]), pk2(f1[2], f1[3])};
        }
        rg[ut]     = MFMA(W0f[0], xb, rg[ut]);
        rg[4 + ut] = MFMA(W0f[1], xb, rg[4 + ut]);
    }
}

// conv epilogue: rg + bias -> Tlds (staggered rows), direct b16 scatter
DEVINL void conv_epi(const f32x4 (&rg)[8], unsigned short* TldsH, const float* bias,
                     int w, int g, int c15)
{
    #pragma unroll
    for (int m2 = 0; m2 < 2; ++m2) {
        const int chb = (2 * w + m2) * 16;
        f32x4 bb = *(const f32x4*)&bias[chb + g * 4];
        #pragma unroll
        for (int ut = 0; ut < 4; ++ut) {
            const int u = ut * 16 + c15;
            #pragma unroll
            for (int r = 0; r < 4; ++r)
                TldsH[TROW(chb + g * 4 + r) * 2 + u] = bf1(rg[m2 * 4 + ut][r] + bb[r]);
        }
    }
}

// mix: rg[mt] = T2_tile x Amix^T   (vertex = lane c15, wave owns v-tile w)
DEVINL void do_mix(f32x4 (&rg)[8], const unsigned* Tlds, const unsigned* Amlds,
                   int w, int g, int c15)
{
    const int vrow = (w * 16 + c15) * TS + g * 4;
    u32x4 bf0 = *(const u32x4*)&Amlds[vrow];
    u32x4 bf1v = *(const u32x4*)&Amlds[vrow + 16];
    #pragma unroll
    for (int mt = 0; mt < 8; ++mt) {
        const int crow = TROW(mt * 16 + c15) + g * 4;
        u32x4 a0 = *(const u32x4*)&Tlds[crow];
        u32x4 a1 = *(const u32x4*)&Tlds[crow + 16];
        f32x4 a = {0.f, 0.f, 0.f, 0.f};
        a = MFMA(a0, bf0, a);
        a = MFMA(a1, bf1v, a);
        rg[mt] = a;
    }
}

// mix epilogue: LN (in-wave) + relu + residual -> Rf; optionally write H to LDS
DEVINL void mix_epi(const f32x4 (&rg)[8], float (&Rf)[8][4], unsigned* Hlds,
                    const float* gam, const float* bet, bool resid, bool writeH,
                    int w, int g, int c15)
{
    float s = 0.f, q = 0.f;
    #pragma unroll
    for (int mt = 0; mt < 8; ++mt)
        #pragma unroll
        for (int r = 0; r < 4; ++r) { float x = rg[mt][r]; s += x; q = fmaf(x, x, q); }
    s += __shfl_xor(s, 16); s += __shfl_xor(s, 32);
    q += __shfl_xor(q, 16); q += __shfl_xor(q, 32);
    const float m   = s * (1.f / 128.f);
    const float var = q * (1.f / 128.f) - m * m;
    const float rs  = rsqrtf(var + 1e-5f);
    const int v = w * 16 + c15;
    #pragma unroll
    for (int mt = 0; mt < 8; ++mt) {
        f32x4 gc = *(const f32x4*)&gam[mt * 16 + g * 4];
        f32x4 bc = *(const f32x4*)&bet[mt * 16 + g * 4];
        #pragma unroll
        for (int r = 0; r < 4; ++r) {
            float val = fmaxf((rg[mt][r] - m) * rs * gc[r] + bc[r], 0.f);
            if (resid) val += Rf[mt][r];
            Rf[mt][r] = val;
        }
        if (writeH) {
            u32x2 pr;
            pr[0] = pk2(Rf[mt][0], Rf[mt][1]);
            pr[1] = pk2(Rf[mt][2], Rf[mt][3]);
            *(u32x2*)&Hlds[v * HS + mt * 8 + g * 2] = pr;
        }
    }
}

// ---------------- kernel A ---------------------------------------------------
__global__ __launch_bounds__(256, 3) void gcn_mfma(
    const float* __restrict__ X, const float* __restrict__ A,
    const int* __restrict__ v1i, const int* __restrict__ v2i, const int* __restrict__ seat,
    const float* __restrict__ W0, const float* __restrict__ b0v,
    const float* __restrict__ g0v, const float* __restrict__ be0,
    const unsigned* __restrict__ W1G, const float* __restrict__ b1v,
    const float* __restrict__ g1v, const float* __restrict__ be1,
    const unsigned* __restrict__ W2G, const float* __restrict__ b2v,
    const float* __restrict__ g2v, const float* __restrict__ be2,
    const float* __restrict__ semb, float* __restrict__ hws, int spb)
{
    __shared__ unsigned Tlds[128 * TS + 4];  // 18.4KB (staggered rows)
    __shared__ unsigned Hlds[64 * HS];       // 17.4KB
    __shared__ unsigned Amlds[64 * TS];      // 9.2KB
    __shared__ float    PrmL[9][128];        // 4.6KB
    __shared__ float    Sm[4][128];          // 2KB
    __shared__ unsigned long long WpS[2];    // laundered W-frag pointers

    const int tid = threadIdx.x;
    const int l = tid & 63, w = tid >> 6, g = l >> 4, c15 = l & 15;

    if (tid < 128) {
        const int c = tid;
        PrmL[0][c] = b0v[c]; PrmL[1][c] = b1v[c]; PrmL[2][c] = b2v[c];
        PrmL[3][c] = g0v[c]; PrmL[4][c] = g1v[c]; PrmL[5][c] = g2v[c];
        PrmL[6][c] = be0[c]; PrmL[7][c] = be1[c]; PrmL[8][c] = be2[c];
    }
    if (tid == 0) {
        WpS[0] = (unsigned long long)W1G;
        WpS[1] = (unsigned long long)W2G;
    }
    for (int p = tid; p < 64 * TS; p += 256) {
        const int v = p / TS, uc = p % TS;
        unsigned val = 0u;
        if (v < 54 && uc < 27) {
            const int u = uc * 2;
            const float a0 = A[v * 54 + u];
            const float a1 = (u + 1 < 54) ? A[v * 54 + u + 1] : 0.f;
            val = pk2(a0, a1);
        }
        Amlds[p] = val;
    }

    // W0 fragments resident (8 VGPRs)
    u32x4 W0f[2];
    #pragma unroll
    for (int m2 = 0; m2 < 2; ++m2) {
        const int ch = (2 * w + m2) * 16 + c15;
        unsigned t0[4];
        #pragma unroll
        for (int jj = 0; jj < 4; ++jj) {
            const int k = g * 8 + 2 * jj;
            t0[jj] = (g < 2) ? pk2(W0[k * 128 + ch], W0[(k + 1) * 128 + ch]) : 0u;
        }
        W0f[m2] = (u32x4){t0[0], t0[1], t0[2], t0[3]};
    }
    __syncthreads();

    float Rf[8][4];
    f32x4 rg[8];     // unified conv/mix accumulators

    // ---- prologue: conv0 of sample 0 ----
    conv0g(rg, X, blockIdx.x, W0f, g, c15);
    conv_epi(rg, (unsigned short*)Tlds, &PrmL[0][0], w, g, c15);
    __syncthreads();   // Tlds(s0) ready

    #pragma unroll 1
    for (int it = 0; it < spb; ++it) {
        const int n = blockIdx.x + gridDim.x * it;

        // laundered pointers -> loads reload from L2, never LICM'd into regs
        const u32x4* W1p = (const u32x4*)(((volatile unsigned long long*)WpS)[0]);
        const u32x4* W2p = (const u32x4*)(((volatile unsigned long long*)WpS)[1]);

        // ---- layer 0: mix of conv0 results ----
        do_mix(rg, Tlds, Amlds, w, g, c15);
        mix_epi(rg, Rf, Hlds, &PrmL[3][0], &PrmL[6][0], false, true, w, g, c15);
        __syncthreads();

        // ---- layer 1 ----
        conv12g(rg, Hlds, W1p, w, g, c15, l);
        conv_epi(rg, (unsigned short*)Tlds, &PrmL[1][0], w, g, c15);
        __syncthreads();
        do_mix(rg, Tlds, Amlds, w, g, c15);
        mix_epi(rg, Rf, Hlds, &PrmL[4][0], &PrmL[7][0], true, true, w, g, c15);
        __syncthreads();

        // ---- layer 2 (writes H to Hlds for the mean) ----
        conv12g(rg, Hlds, W2p, w, g, c15, l);
        conv_epi(rg, (unsigned short*)Tlds, &PrmL[2][0], w, g, c15);
        __syncthreads();
        do_mix(rg, Tlds, Amlds, w, g, c15);
        mix_epi(rg, Rf, Hlds, &PrmL[5][0], &PrmL[8][0], true, true, w, g, c15);
        __syncthreads();   // Hlds final ready; Tlds consumed

        // ---- MERGED PHASE: head(n) || conv0(n+1) -> one barrier ----
        const int v1 = v1i[n], v2 = v2i[n];
        int st = seat[n];
        st = st < 0 ? 0 : (st > 3 ? 3 : st);
        float* hr = hws + (size_t)n * HROW;
        const int v = w * 16 + c15;

        // v1/v2 gather from fp32 Rf (exact; before Rf is overwritten)
        if (v == v1 || v == v2) {
            #pragma unroll
            for (int mt = 0; mt < 8; ++mt) {
                f32x4 t;
                #pragma unroll
                for (int r = 0; r < 4; ++r) t[r] = Rf[mt][r];
                if (v == v1) *(f32x4*)&hr[mt * 16 + g * 4] = t;
                if (v == v2) *(f32x4*)&hr[128 + mt * 16 + g * 4] = t;
            }
        }

        // mean partials from Hlds: thread = (row-quarter w, ch-pair)
        {
            const int pair = tid & 63;
            const int nv = (w == 3) ? 6 : 16;   // rows 48..53 only in quarter 3
            float s0 = 0.f, s1 = 0.f;
            const unsigned* hb = &Hlds[(w * 16) * HS + pair];
            for (int r = 0; r < nv; ++r) {
                const unsigned u = hb[r * HS];
                s0 += __uint_as_float(u << 16);
                s1 += __uint_as_float(u & 0xffff0000u);
            }
            Sm[w][2 * pair]     = s0;
            Sm[w][2 * pair + 1] = s1;
        }
        if (tid < 8)       hr[384 + tid] = semb[st * 8 + tid];
        else if (tid < 16) hr[384 + tid] = 0.f;   // pad cols 392..399

        // conv0 of next sample (X load latency hides under head work above)
        if (it + 1 < spb) {
            conv0g(rg, X, n + (int)gridDim.x, W0f, g, c15);
            conv_epi(rg, (unsigned short*)Tlds, &PrmL[0][0], w, g, c15);
        }
        __syncthreads();   // Sm ready AND Tlds(n+1) ready — merged barrier

        if (tid < 128) {
            const float mn = (Sm[0][tid] + Sm[1][tid] + Sm[2][tid] + Sm[3][tid]) * (1.f / 54.f);
            hr[256 + tid] = mn;
        }
    }
}

// ---------------- weight frag init (runs once per launch, ~us) ---------------
__global__ void head_frag_init(const float* __restrict__ mW1,
                               const float* __restrict__ rW1,
                               const float* __restrict__ mW2,
                               const float* __restrict__ W1t,
                               const float* __restrict__ W2t,
                               unsigned* __restrict__ W1h, unsigned* __restrict__ W1l,
                               unsigned* __restrict__ R1h, unsigned* __restrict__ W2h,
                               unsigned* __restrict__ W1G, unsigned* __restrict__ W2G)
{
    const int t = blockIdx.x * 256 + threadIdx.x;
    if (t < 13 * 128 * 16) {
        const int j = t & 3, g = (t >> 2) & 3, col = (t >> 4) & 127, ks = t >> 11;
        const int k = ks * 32 + g * 8 + 2 * j;
        const float w0 = (k < 392)     ? mW1[k * 128 + col]       : 0.f;
        const float w1 = (k + 1 < 392) ? mW1[(k + 1) * 128 + col] : 0.f;
        const unsigned h0 = bfr(w0), h1 = bfr(w1);
        const float l0 = w0 - __uint_as_float(h0 << 16);
        const float l1 = w1 - __uint_as_float(h1 << 16);
        const int idx = ((ks * 8 + (col >> 4)) * 64 + g * 16 + (col & 15)) * 4 + j;
        W1h[idx] = h0 | (h1 << 16);
        W1l[idx] = pk2(l0, l1);
    }
    if (t < 13 * 64 * 16) {
        const int j = t & 3, g = (t >> 2) & 3, col = (t >> 4) & 63, ks = t >> 10;
        const int k = ks * 32 + g * 8 + 2 * j;
        const float w0 = (k < 392)     ? rW1[k * 64 + col]       : 0.f;
        const float w1 = (k + 1 < 392) ? rW1[(k + 1) * 64 + col] : 0.f;
        const int idx = ((ks * 4 + (col >> 4)) * 64 + g * 16 + (col & 15)) * 4 + j;
        R1h[idx] = pk2(w0, w1);
    }
    if (t < 4 * 64 * 16) {
        const int j = t & 3, g = (t >> 2) & 3, col = (t >> 4) & 63, ks2 = t >> 10;
        const int k = ks2 * 32 + g * 8 + 2 * j;
        const int idx = ((ks2 * 4 + (col >> 4)) * 64 + g * 16 + (col & 15)) * 4 + j;
        W2h[idx] = pk2(mW2[k * 64 + col], mW2[(k + 1) * 64 + col]);
    }
    // trunk conv W1/W2 A-fragments: idx = ((ct*4+ks)*64 + lane)*4 + j
    if (t < 8 * 4 * 64 * 4) {
        const int j = t & 3, lane = (t >> 2) & 63, ks = (t >> 8) & 3, ct = t >> 10;
        const int g2 = lane >> 4, c15 = lane & 15;
        const int k = ks * 32 + g2 * 8 + 2 * j;
        const int ch = ct * 16 + c15;
        W1G[t] = pk2(W1t[k * 128 + ch], W1t[(k + 1) * 128 + ch]);
        W2G[t] = pk2(W2t[k * 128 + ch], W2t[(k + 1) * 128 + ch]);
    }
}

// ---------------- kernel B: batched head, weights from global frags ----------
__global__ __launch_bounds__(256, 2) void head_mfma(
    const float* __restrict__ hws,
    const unsigned* __restrict__ W1hG, const unsigned* __restrict__ W1lG,
    const unsigned* __restrict__ R1hG, const unsigned* __restrict__ W2hG,
    const float* __restrict__ mb1, const float* __restrict__ mb2,
    const float* __restrict__ mW3, const float* __restrict__ mb3,
    const float* __restrict__ rb1, const float* __restrict__ rW2,
    const float* __restrict__ rb2,
    float* __restrict__ out, int N)
{
    __shared__ u32x4 Zh[16 * 64];         // 16KB

    const int tid = threadIdx.x, l = tid & 63, w = tid >> 6, g = l >> 4, c15 = l & 15;
    const int row = blockIdx.x * 64 + w * 16 + c15;

    const u32x4* W1h4 = (const u32x4*)W1hG;
    const u32x4* W1l4 = (const u32x4*)W1lG;
    const u32x4* R1h4 = (const u32x4*)R1hG;
    const u32x4* W2h4 = (const u32x4*)W2hG;

    f32x4 z1[8], rr[4];
    #pragma unroll
    for (int i = 0; i < 8; ++i) z1[i] = (f32x4){0.f, 0.f, 0.f, 0.f};
    #pragma unroll
    for (int i = 0; i < 4; ++i) rr[i] = (f32x4){0.f, 0.f, 0.f, 0.f};

    #pragma unroll 1
    for (int ks = 0; ks < 13; ++ks) {
        const float* hp = hws + (size_t)row * HROW + ks * 32 + g * 8;
        f32x4 f0 = *(const f32x4*)hp, f1 = *(const f32x4*)(hp + 4);
        float vv[8] = {f0[0], f0[1], f0[2], f0[3], f1[0], f1[1], f1[2], f1[3]};
        unsigned th[4], tl[4];
        #pragma unroll
        for (int jj = 0; jj < 4; ++jj) {
            unsigned ha = bfr(vv[2 * jj]), hb = bfr(vv[2 * jj + 1]);
            th[jj] = ha | (hb << 16);
            tl[jj] = pk2(vv[2 * jj] - __uint_as_float(ha << 16),
                         vv[2 * jj + 1] - __uint_as_float(hb << 16));
        }
        u32x4 ah = (u32x4){th[0], th[1], th[2], th[3]};
        u32x4 al = (u32x4){tl[0], tl[1], tl[2], tl[3]};
        #pragma unroll
        for (int nt = 0; nt < 8; ++nt) {
            u32x4 bh = W1h4[(ks * 8 + nt) * 64 + l];
            u32x4 bl = W1l4[(ks * 8 + nt) * 64 + l];
            f32x4 a = z1[nt];
            a = MFMA(ah, bh, a); a = MFMA(ah, bl, a); a = MFMA(al, bh, a);
            z1[nt] = a;
        }
        #pragma unroll
        for (int nt = 0; nt < 4; ++nt)
            rr[nt] = MFMA(ah, R1h4[(ks * 4 + nt) * 64 + l], rr[nt]);
    }

    float rp[4] = {0.f, 0.f, 0.f, 0.f};
    #pragma unroll
    for (int nt = 0; nt < 4; ++nt) {
        int c = nt * 16 + c15;
        float rb = rb1[c], rw = rW2[c];
        #pragma unroll
        for (int r = 0; r < 4; ++r) rp[r] += fmaxf(rr[nt][r] + rb, 0.f) * rw;
    }
    #pragma unroll
    for (int r = 0; r < 4; ++r) {
        float p = rp[r];
        #pragma unroll
        for (int m = 1; m <= 8; m <<= 1) p += __shfl_xor(p, m);
        if (c15 == 0) {
            int orow = blockIdx.x * 64 + w * 16 + g * 4 + r;
            out[N + orow] = 1.f / (1.f + expf(-(p + rb2[0])));
        }
    }

    {
        unsigned short* zp = (unsigned short*)Zh;
        #pragma unroll
        for (int nt = 0; nt < 8; ++nt) {
            int c = nt * 16 + c15;
            float bb = mb1[c];
            #pragma unroll
            for (int r = 0; r < 4; ++r) {
                float v = fmaxf(z1[nt][r] + bb, 0.f);
                int lanep = ((nt * 2 + (c15 >> 3)) & 3) * 16 + g * 4 + r;
                zp[((w * 4 + (nt >> 1)) * 64 + lanep) * 8 + (c15 & 7)] = (unsigned short)bfr(v);
            }
        }
    }
    __syncthreads();

    f32x4 z2a[4];
    #pragma unroll
    for (int i = 0; i < 4; ++i) z2a[i] = (f32x4){0.f, 0.f, 0.f, 0.f};
    #pragma unroll
    for (int ks2 = 0; ks2 < 4; ++ks2) {
        u32x4 za = Zh[(w * 4 + ks2) * 64 + l];
        #pragma unroll
        for (int nt2 = 0; nt2 < 4; ++nt2)
            z2a[nt2] = MFMA(za, W2h4[(ks2 * 4 + nt2) * 64 + l], z2a[nt2]);
    }
    float wp[4] = {0.f, 0.f, 0.f, 0.f};
    #pragma unroll
    for (int nt2 = 0; nt2 < 4; ++nt2) {
        int c = nt2 * 16 + c15;
        float bb = mb2[c], w3 = mW3[c];
        #pragma unroll
        for (int r = 0; r < 4; ++r) wp[r] += fmaxf(z2a[nt2][r] + bb, 0.f) * w3;
    }
    #pragma unroll
    for (int r = 0; r < 4; ++r) {
        float p = wp[r];
        #pragma unroll
        for (int m = 1; m <= 8; m <<= 1) p += __shfl_xor(p, m);
        if (c15 == 0) {
            int orow = blockIdx.x * 64 + w * 16 + g * 4 + r;
            out[orow] = p + mb3[0];
        }
    }
}

extern "C" void kernel_launch(void* const* d_in, const int* in_sizes, int n_in,
                              void* d_out, int out_size, void* d_ws, size_t ws_size,
                              hipStream_t stream) {
    const float* X        = (const float*)d_in[0];
    const float* A        = (const float*)d_in[1];
    const int*   v1_idx   = (const int*)d_in[2];
    const int*   v2_idx   = (const int*)d_in[3];
    const int*   seat     = (const int*)d_in[4];
    const float* W0       = (const float*)d_in[5];
    const float* b0       = (const float*)d_in[6];
    const float* g0       = (const float*)d_in[7];
    const float* be0      = (const float*)d_in[8];
    const float* W1       = (const float*)d_in[9];
    const float* b1       = (const float*)d_in[10];
    const float* g1       = (const float*)d_in[11];
    const float* be1      = (const float*)d_in[12];
    const float* W2       = (const float*)d_in[13];
    const float* b2       = (const float*)d_in[14];
    const float* g2       = (const float*)d_in[15];
    const float* be2      = (const float*)d_in[16];
    const float* seat_emb = (const float*)d_in[17];
    const float* mW1      = (const float*)d_in[18];
    const float* mb1      = (const float*)d_in[19];
    const float* mW2      = (const float*)d_in[20];
    const float* mb2      = (const float*)d_in[21];
    const float* mW3      = (const float*)d_in[22];
    const float* mb3      = (const float*)d_in[23];
    const float* rW1      = (const float*)d_in[24];
    const float* rb1      = (const float*)d_in[25];
    const float* rW2      = (const float*)d_in[26];
    const float* rb2      = (const float*)d_in[27];

    const int N = in_sizes[2];           // 16384
    float* out = (float*)d_out;

    // ws layout: hws [N][400] fp32 | W1h | W1l | R1h | W2h | W1G | W2G
    float*    hws = (float*)d_ws;
    unsigned* W1h = (unsigned*)((char*)d_ws + (size_t)N * HROW * 4);
    unsigned* W1l = W1h + 26624;
    unsigned* R1h = W1l + 26624;
    unsigned* W2h = R1h + 13312;
    unsigned* W1G = W2h + 4096;
    unsigned* W2G = W1G + 8192;          // total ~26.56MB (< proven 27.3MB)

    head_frag_init<<<104, 256, 0, stream>>>(mW1, rW1, mW2, W1, W2,
                                            W1h, W1l, R1h, W2h, W1G, W2G);

    const int spb = 8;
    const int gridA = N / spb;           // 2048
    gcn_mfma<<<gridA, 256, 0, stream>>>(
        X, A, v1_idx, v2_idx, seat,
        W0, b0, g0, be0, W1G, b1, g1, be1, W2G, b2, g2, be2,
        seat_emb, hws, spb);

    const int gridB = N / 64;            // 256
    head_mfma<<<gridB, 256, 0, stream>>>(
        hws, W1h, W1l, R1h, W2h,
        mb1, mb2, mW3, mb3, rb1, rW2, rb2, out, N);
}